// Round 7
// baseline (7771.954 us; speedup 1.0000x reference)
//
#include <hip/hip_runtime.h>
#include <cstdint>
#include <cstddef>

#define B_   4
#define V_   50000
#define VP_  50048                       // 782*64  (fb/vf row count)
#define VPT_ 50176                       // 784*64 = 196*256 (evT/mxT v-stride)
#define K_   128
#define C_   128
#define NNZ_ 800000
#define HID_ 256

#define NB_   391                        // buckets of 128 rows: ceil(50000/128)
#define CAP_  2432                       // per-(d,bucket) entry capacity (mean 2048, +8.5 sigma)
#define CH_   4096                       // entries per binfill block
#define NBF_  196                        // ceil(NNZ_/CH_)

typedef __attribute__((ext_vector_type(8))) short short8;
typedef __attribute__((ext_vector_type(4))) float f32x4;
typedef unsigned short us;

__device__ __forceinline__ us f2b(float f) {
    union { float f; unsigned u; } v; v.f = f;
    unsigned r = v.u + 0x7fffu + ((v.u >> 16) & 1u);
    return (us)(r >> 16);
}
__device__ __forceinline__ float b2f(us h) {
    union { unsigned u; float f; } v; v.u = ((unsigned)h) << 16; return v.f;
}
__device__ __forceinline__ unsigned pk(float lo, float hi) {
    return (unsigned)f2b(lo) | ((unsigned)f2b(hi) << 16);
}
__device__ __forceinline__ short8 cvt8(float4 p0, float4 p1) {
    union { unsigned u[4]; short8 s; } r;
    r.u[0] = pk(p0.x, p0.y); r.u[1] = pk(p0.z, p0.w);
    r.u[2] = pk(p1.x, p1.y); r.u[3] = pk(p1.z, p1.w);
    return r.s;
}

// ============================================================================
// k_cvt_all: W0/W1 bf16 convert + Aw permuted bf16 convert (one dispatch)
// ============================================================================
__global__ __launch_bounds__(256) void k_cvt_all(
    const float* __restrict__ W0, const float* __restrict__ W1,
    const float* __restrict__ Aw,
    us* __restrict__ W0b, us* __restrict__ W1b, us* __restrict__ Awb)
{
    int t = blockIdx.x * 256 + threadIdx.x;          // 163840 threads total
    if (t < 16384) {
        const float* src; us* dst; int i8;
        if (t < 12288) { i8 = t * 8;            src = W0 + i8; dst = W0b + i8; }
        else           { i8 = (t - 12288) * 8;  src = W1 + i8; dst = W1b + i8; }
        float4 x0 = *(const float4*)src;
        float4 x1 = *(const float4*)(src + 4);
        uint4 u;
        u.x = pk(x0.x, x0.y); u.y = pk(x0.z, x0.w);
        u.z = pk(x1.x, x1.y); u.w = pk(x1.z, x1.w);
        *(uint4*)dst = u;
    } else {
        int p  = t - 16384;                          // < 147456
        int p1 = p / 384, p2 = p - p1 * 384;
        int q1 = 3 * (p1 & 127) + (p1 >> 7);
        int q2 = 3 * (p2 & 127) + (p2 >> 7);
        Awb[p] = f2b(Aw[q1 * 384 + q2]);
    }
}

// ============================================================================
// k_trans: fused transpose kernel (known-good from round 6)
// ============================================================================
__global__ __launch_bounds__(256) void k_trans(
    const float* __restrict__ x_in, const float* __restrict__ mass,
    const float* __restrict__ evecs,
    us* __restrict__ mxT, us* __restrict__ evT, us* __restrict__ fb, int b)
{
    const int v0  = blockIdx.x * 64;
    const int tid = threadIdx.x;
    __shared__ us ts[128][72];

#pragma unroll
    for (int it = 0; it < 8; ++it) {
        int f   = tid + it * 256;
        int row = f >> 5;
        int col = (f & 31) * 4;
        int v   = v0 + row;
        float4 x = make_float4(0.f, 0.f, 0.f, 0.f);
        float  m = 0.f;
        if (v < V_) {
            x = *(const float4*)&x_in[((size_t)b * V_ + v) * C_ + col];
            m = mass[b * V_ + v];
            uint2 u; u.x = pk(x.x, x.y); u.y = pk(x.z, x.w);
            *(uint2*)&fb[(size_t)v * 384 + col] = u;
        }
        ts[col + 0][row] = f2b(x.x * m); ts[col + 1][row] = f2b(x.y * m);
        ts[col + 2][row] = f2b(x.z * m); ts[col + 3][row] = f2b(x.w * m);
    }
    __syncthreads();
    {
        int c = tid >> 1, half = tid & 1;
#pragma unroll
        for (int q = 0; q < 4; ++q) {
            uint4 u = *(const uint4*)&ts[c][half * 32 + q * 8];
            *(uint4*)&mxT[(size_t)c * VPT_ + v0 + half * 32 + q * 8] = u;
        }
    }
    __syncthreads();

#pragma unroll
    for (int it = 0; it < 8; ++it) {
        int f   = tid + it * 256;
        int row = f >> 5;
        int col = (f & 31) * 4;
        int v   = v0 + row;
        float4 e = (v < V_)
            ? *(const float4*)&evecs[((size_t)b * V_ + v) * K_ + col]
            : make_float4(0.f, 0.f, 0.f, 0.f);
        ts[col + 0][row] = f2b(e.x); ts[col + 1][row] = f2b(e.y);
        ts[col + 2][row] = f2b(e.z); ts[col + 3][row] = f2b(e.w);
    }
    __syncthreads();
    {
        int k = tid >> 1, half = tid & 1;
#pragma unroll
        for (int q = 0; q < 4; ++q) {
            uint4 u = *(const uint4*)&ts[k][half * 32 + q * 8];
            *(uint4*)&evT[(size_t)k * VPT_ + v0 + half * 32 + q * 8] = u;
        }
    }
}

// ============================================================================
// k_spec_mfma: x_spec[b,k,c] += sum_{v-slab} evT[k][v] * mxT[c][v]   (MFMA)
// ============================================================================
__global__ __launch_bounds__(256) void k_spec_mfma(
    const us* __restrict__ evT, const us* __restrict__ mxT,
    float* __restrict__ x_spec, int b)
{
    const int vb  = blockIdx.x * 256;
    const int tid = threadIdx.x;
    const int w   = tid >> 6;
    const int lr  = tid & 15;
    const int lk  = (tid & 63) >> 4;

    f32x4 z = {0.f, 0.f, 0.f, 0.f};
    f32x4 acc[2][8];
#pragma unroll
    for (int mi = 0; mi < 2; ++mi)
#pragma unroll
        for (int ni = 0; ni < 8; ++ni) acc[mi][ni] = z;

#pragma unroll 2
    for (int s = 0; s < 8; ++s) {
        int vo = vb + s * 32 + lk * 8;
        short8 a[2], bf[8];
#pragma unroll
        for (int mi = 0; mi < 2; ++mi)
            a[mi] = *(const short8*)&evT[(size_t)(w * 32 + mi * 16 + lr) * VPT_ + vo];
#pragma unroll
        for (int ni = 0; ni < 8; ++ni)
            bf[ni] = *(const short8*)&mxT[(size_t)(ni * 16 + lr) * VPT_ + vo];
#pragma unroll
        for (int mi = 0; mi < 2; ++mi)
#pragma unroll
            for (int ni = 0; ni < 8; ++ni)
                acc[mi][ni] = __builtin_amdgcn_mfma_f32_16x16x32_bf16(
                    a[mi], bf[ni], acc[mi][ni], 0, 0, 0);
    }
#pragma unroll
    for (int mi = 0; mi < 2; ++mi)
#pragma unroll
        for (int ni = 0; ni < 8; ++ni)
#pragma unroll
            for (int r = 0; r < 4; ++r) {
                int k = w * 32 + mi * 16 + lk * 4 + r;
                int c = ni * 16 + lr;
                atomicAdd(&x_spec[((size_t)b * K_ + k) * C_ + c], acc[mi][ni][r]);
            }
}

// ============================================================================
// k_scale2: spec_t[c][k] = bf16( exp(-evals[b,k]*max(dt[c],1e-8)) * x_spec[b,k,c] )
// ============================================================================
__global__ __launch_bounds__(256) void k_scale2(
    const float* __restrict__ evals, const float* __restrict__ dt,
    const float* __restrict__ x_spec, us* __restrict__ spec_t, int b)
{
    int i = blockIdx.x * 256 + threadIdx.x;    // < 16384
    int c = i >> 7;
    int k = i & 127;
    float t = fmaxf(dt[c], 1e-8f);
    float v = __expf(-evals[b * K_ + k] * t) * x_spec[((size_t)b * K_ + k) * C_ + c];
    spec_t[i] = f2b(v);
}

// ============================================================================
// k_frombasis_mfma: fb[v][128+c] = bf16( sum_k evecs[b,v,k] * spec_t[c][k] )
// ============================================================================
__global__ __launch_bounds__(256) void k_frombasis_mfma(
    const float* __restrict__ evecs, const us* __restrict__ spec_t,
    us* __restrict__ fb, int b)
{
    const int v0  = blockIdx.x * 64;
    const int tid = threadIdx.x;
    const int w   = tid >> 6;
    const int lr  = tid & 15;
    const int lk  = (tid & 63) >> 4;

    f32x4 z = {0.f, 0.f, 0.f, 0.f};
    f32x4 acc[4][2];
#pragma unroll
    for (int mi = 0; mi < 4; ++mi)
#pragma unroll
        for (int ni = 0; ni < 2; ++ni) acc[mi][ni] = z;

#pragma unroll
    for (int ks = 0; ks < 4; ++ks) {
        int ko = ks * 32 + lk * 8;
        short8 a[4], bf[2];
#pragma unroll
        for (int mi = 0; mi < 4; ++mi) {
            int v = v0 + mi * 16 + lr;
            float4 p0 = make_float4(0.f, 0.f, 0.f, 0.f);
            float4 p1 = make_float4(0.f, 0.f, 0.f, 0.f);
            if (v < V_) {
                const float* src = &evecs[((size_t)b * V_ + v) * K_ + ko];
                p0 = *(const float4*)src;
                p1 = *(const float4*)(src + 4);
            }
            a[mi] = cvt8(p0, p1);
        }
#pragma unroll
        for (int ni = 0; ni < 2; ++ni)
            bf[ni] = *(const short8*)&spec_t[(size_t)(w * 32 + ni * 16 + lr) * K_ + ko];
#pragma unroll
        for (int mi = 0; mi < 4; ++mi)
#pragma unroll
            for (int ni = 0; ni < 2; ++ni)
                acc[mi][ni] = __builtin_amdgcn_mfma_f32_16x16x32_bf16(
                    a[mi], bf[ni], acc[mi][ni], 0, 0, 0);
    }
#pragma unroll
    for (int mi = 0; mi < 4; ++mi)
#pragma unroll
        for (int ni = 0; ni < 2; ++ni)
#pragma unroll
            for (int r = 0; r < 4; ++r) {
                int v = v0 + mi * 16 + lk * 4 + r;
                int c = w * 32 + ni * 16 + lr;
                if (v < V_) fb[(size_t)v * 384 + 128 + c] = f2b(acc[mi][ni][r]);
            }
}

// ============================================================================
// k_binfill: LDS-binned bucket scatter.
// Block = CH_ edges of direction d. Histogram buckets (q=r>>7) in LDS, scan,
// reorder into LDS staging, flush each bucket as a contiguous run into its
// global region chunk[(d*NB_+q)*CAP_ + cursor...]. Entry: {val fp32,
// (q<<23)|(rlow<<16)|col}.
// ============================================================================
__global__ __launch_bounds__(256) void k_binfill(
    const int* __restrict__ r0, const int* __restrict__ r1, const int* __restrict__ r2,
    const int* __restrict__ c0, const int* __restrict__ c1, const int* __restrict__ c2,
    const float* __restrict__ v0, const float* __restrict__ v1, const float* __restrict__ v2,
    uint2* __restrict__ chunk, int* __restrict__ gcnt, int b)
{
    const int d   = blockIdx.y;
    const int e0  = blockIdx.x * CH_;
    const int tid = threadIdx.x;
    const int*   rr = (d == 0) ? r0 : (d == 1) ? r1 : r2;
    const int*   cc = (d == 0) ? c0 : (d == 1) ? c1 : c2;
    const float* vv = (d == 0) ? v0 : (d == 1) ? v1 : v2;

    __shared__ int   hist[NB_];
    __shared__ int   cur[NB_];
    __shared__ int   base[NB_];
    __shared__ int   gbase[NB_];
    __shared__ uint2 buf[CH_];           // 32 KB

    for (int i = tid; i < NB_; i += 256) { hist[i] = 0; cur[i] = 0; }
    __syncthreads();

    int rloc[16];
#pragma unroll
    for (int j = 0; j < 16; ++j) {
        int e = e0 + j * 256 + tid;
        int r = (e < NNZ_) ? rr[(size_t)b * NNZ_ + e] : -1;
        rloc[j] = r;
        if (r >= 0) atomicAdd(&hist[r >> 7], 1);
    }
    __syncthreads();

    // exclusive scan of hist -> base (wave 0: 7 buckets/lane + shfl scan)
    if (tid < 64) {
        int q0 = tid * 7;
        int loc[7];
        int s = 0;
#pragma unroll
        for (int j = 0; j < 7; ++j) {
            int q = q0 + j;
            int h = (q < NB_) ? hist[q] : 0;
            loc[j] = s; s += h;
        }
        int inc = s;
        for (int off = 1; off < 64; off <<= 1) {
            int t = __shfl_up(inc, off, 64);
            if (tid >= off) inc += t;
        }
        int excl = inc - s;
#pragma unroll
        for (int j = 0; j < 7; ++j) {
            int q = q0 + j;
            if (q < NB_) base[q] = excl + loc[j];
        }
    }
    __syncthreads();

    // reorder into LDS staging buffer
#pragma unroll
    for (int j = 0; j < 16; ++j) {
        int r = rloc[j];
        if (r < 0) continue;
        int e = e0 + j * 256 + tid;
        int q = r >> 7;
        int off = atomicAdd(&cur[q], 1);
        int pos = base[q] + off;
        uint2 ent;
        ent.x = __float_as_uint(vv[(size_t)b * NNZ_ + e]);
        ent.y = ((unsigned)q << 23) | ((unsigned)(r & 127) << 16)
              | (unsigned)cc[(size_t)b * NNZ_ + e];
        buf[pos] = ent;
    }
    __syncthreads();

    // reserve global space per bucket
    for (int q = tid; q < NB_; q += 256) {
        int c = cur[q];
        if (c > 0) gbase[q] = atomicAdd(&gcnt[d * NB_ + q], c);
    }
    __syncthreads();

    // flush: consecutive i -> mostly same bucket -> coalesced runs
    const int tot = min(CH_, NNZ_ - e0);
#pragma unroll
    for (int j = 0; j < 16; ++j) {
        int i = tid + j * 256;
        if (i >= tot) break;
        uint2 ent = buf[i];
        int q   = ent.y >> 23;
        int dst = gbase[q] + (i - base[q]);
        if (dst < CAP_)
            chunk[(size_t)(d * NB_ + q) * CAP_ + dst] =
                make_uint2(ent.x, ent.y & 0x7fffffu);
    }
}

// ============================================================================
// k_gather2: block = (bucket q, direction d). Accumulate val*x_diffuse[col]
// into a 128x128 fp32 LDS tile (LDS float atomics), write vf coalesced.
// ============================================================================
__global__ __launch_bounds__(256) void k_gather2(
    const uint2* __restrict__ chunk, const int* __restrict__ gcnt,
    const us* __restrict__ fb, us* __restrict__ vf)
{
    const int q    = blockIdx.x;
    const int d    = blockIdx.y;
    const int tid  = threadIdx.x;
    const int wave = tid >> 6;
    const int lane = tid & 63;

    __shared__ float acc[128][130];
    for (int i = tid; i < 128 * 130; i += 256) ((float*)acc)[i] = 0.f;
    __syncthreads();

    const int cnt = min(gcnt[d * NB_ + q], CAP_);
    const uint2* cb = chunk + (size_t)(d * NB_ + q) * CAP_;
    const int lo2 = lane * 2;

    int i = wave;
    for (; i + 4 < cnt; i += 8) {
        uint2 e0 = cb[i];
        uint2 e1 = cb[i + 4];
        unsigned u0 = *(const unsigned*)&fb[(size_t)(e0.y & 0xffffu) * 384 + 128 + lo2];
        unsigned u1 = *(const unsigned*)&fb[(size_t)(e1.y & 0xffffu) * 384 + 128 + lo2];
        float va = __uint_as_float(e0.x);
        float vb2 = __uint_as_float(e1.x);
        int ra = (e0.y >> 16) & 127;
        int rb = (e1.y >> 16) & 127;
        atomicAdd(&acc[ra][lo2 + 0], va * b2f((us)(u0 & 0xffffu)));
        atomicAdd(&acc[ra][lo2 + 1], va * b2f((us)(u0 >> 16)));
        atomicAdd(&acc[rb][lo2 + 0], vb2 * b2f((us)(u1 & 0xffffu)));
        atomicAdd(&acc[rb][lo2 + 1], vb2 * b2f((us)(u1 >> 16)));
    }
    for (; i < cnt; i += 4) {
        uint2 e0 = cb[i];
        unsigned u0 = *(const unsigned*)&fb[(size_t)(e0.y & 0xffffu) * 384 + 128 + lo2];
        float va = __uint_as_float(e0.x);
        int ra = (e0.y >> 16) & 127;
        atomicAdd(&acc[ra][lo2 + 0], va * b2f((us)(u0 & 0xffffu)));
        atomicAdd(&acc[ra][lo2 + 1], va * b2f((us)(u0 >> 16)));
    }
    __syncthreads();

    // write out: vf[q*128+rlow][d*128 + 2p..2p+1]
    for (int i2 = tid; i2 < 128 * 64; i2 += 256) {
        int rlow = i2 >> 6;
        int p    = i2 & 63;
        int r    = q * 128 + rlow;
        if (r < V_)
            *(unsigned*)&vf[(size_t)r * 384 + d * 128 + 2 * p] =
                pk(acc[rlow][2 * p], acc[rlow][2 * p + 1]);
    }
}

// ============================================================================
// k_gf_mfma: Av' = vf @ Awb^T (MFMA bf16), then
// f[v][256+c] = bf16(tanh(sum_d Av'[v][d*128+c] * vf[v][d*128+c]))
// ============================================================================
__global__ __launch_bounds__(256) void k_gf_mfma(
    const us* __restrict__ vf, const us* __restrict__ Awb,
    us* __restrict__ fb)
{
    const int v0  = blockIdx.x * 64;
    const int tid = threadIdx.x;
    const int w   = tid >> 6;
    const int lr  = tid & 15;
    const int lk  = (tid & 63) >> 4;

    f32x4 z = {0.f, 0.f, 0.f, 0.f};
    f32x4 acc[4][3][2];
#pragma unroll
    for (int mi = 0; mi < 4; ++mi)
#pragma unroll
        for (int d = 0; d < 3; ++d)
#pragma unroll
            for (int ci = 0; ci < 2; ++ci) acc[mi][d][ci] = z;

    const us* aa = vf  + (size_t)(v0 + lr) * 384 + lk * 8;
    const us* bb = Awb + (size_t)(w * 32 + lr) * 384 + lk * 8;
#pragma unroll 2
    for (int kc = 0; kc < 12; ++kc) {
        short8 a[4];
#pragma unroll
        for (int mi = 0; mi < 4; ++mi)
            a[mi] = *(const short8*)(aa + mi * (16 * 384) + kc * 32);
        short8 bm[3][2];
#pragma unroll
        for (int d = 0; d < 3; ++d)
#pragma unroll
            for (int ci = 0; ci < 2; ++ci)
                bm[d][ci] = *(const short8*)(bb + (size_t)(d * 128 + ci * 16) * 384 + kc * 32);
#pragma unroll
        for (int mi = 0; mi < 4; ++mi)
#pragma unroll
            for (int d = 0; d < 3; ++d)
#pragma unroll
                for (int ci = 0; ci < 2; ++ci)
                    acc[mi][d][ci] = __builtin_amdgcn_mfma_f32_16x16x32_bf16(
                        a[mi], bm[d][ci], acc[mi][d][ci], 0, 0, 0);
    }
#pragma unroll
    for (int mi = 0; mi < 4; ++mi)
#pragma unroll
        for (int r = 0; r < 4; ++r) {
            int m = mi * 16 + lk * 4 + r;
            int v = v0 + m;
            if (v < V_) {
#pragma unroll
                for (int ci = 0; ci < 2; ++ci) {
                    int c = w * 32 + ci * 16 + lr;
                    float s = 0.f;
#pragma unroll
                    for (int d = 0; d < 3; ++d)
                        s += acc[mi][d][ci][r] * b2f(vf[(size_t)v * 384 + d * 128 + c]);
                    fb[(size_t)v * 384 + 256 + c] = f2b(tanhf(s));
                }
            }
        }
}

// ============================================================================
// k_mlp_mfma: h = relu(f @ W0^T + b0) (bf16, LDS); out = h @ W1^T + b1 + x_in
// ============================================================================
__global__ __launch_bounds__(256) void k_mlp_mfma(
    const us* __restrict__ fb,
    const us* __restrict__ W0b, const float* __restrict__ b0,
    const us* __restrict__ W1b, const float* __restrict__ b1,
    const float* __restrict__ x_in, float* __restrict__ out, int b)
{
    const int v0  = blockIdx.x * 64;
    const int tid = threadIdx.x;
    const int w   = tid >> 6;
    const int lr  = tid & 15;
    const int lk  = (tid & 63) >> 4;

    __shared__ us Hs[64][264];

    f32x4 z = {0.f, 0.f, 0.f, 0.f};
    f32x4 acc[4][4];
#pragma unroll
    for (int mi = 0; mi < 4; ++mi)
#pragma unroll
        for (int ni = 0; ni < 4; ++ni) acc[mi][ni] = z;

    const us* fa = fb  + (size_t)(v0 + lr) * 384 + lk * 8;
    const us* wb = W0b + (size_t)(w * 64 + lr) * 384 + lk * 8;
#pragma unroll 4
    for (int kc = 0; kc < 12; ++kc) {
        short8 a[4], bbf[4];
#pragma unroll
        for (int mi = 0; mi < 4; ++mi)
            a[mi] = *(const short8*)(fa + mi * (16 * 384) + kc * 32);
#pragma unroll
        for (int ni = 0; ni < 4; ++ni)
            bbf[ni] = *(const short8*)(wb + ni * (16 * 384) + kc * 32);
#pragma unroll
        for (int mi = 0; mi < 4; ++mi)
#pragma unroll
            for (int ni = 0; ni < 4; ++ni)
                acc[mi][ni] = __builtin_amdgcn_mfma_f32_16x16x32_bf16(
                    a[mi], bbf[ni], acc[mi][ni], 0, 0, 0);
    }
#pragma unroll
    for (int ni = 0; ni < 4; ++ni) {
        int n = w * 64 + ni * 16 + lr;
        float bias = b0[n];
#pragma unroll
        for (int mi = 0; mi < 4; ++mi)
#pragma unroll
            for (int r = 0; r < 4; ++r) {
                int m = mi * 16 + lk * 4 + r;
                Hs[m][n] = f2b(fmaxf(acc[mi][ni][r] + bias, 0.f));
            }
    }
    __syncthreads();

    f32x4 acc2[4][2];
#pragma unroll
    for (int mi = 0; mi < 4; ++mi)
#pragma unroll
        for (int ni = 0; ni < 2; ++ni) acc2[mi][ni] = z;

    const us* w1b = W1b + (size_t)(w * 32 + lr) * 256 + lk * 8;
#pragma unroll 4
    for (int kc = 0; kc < 8; ++kc) {
        short8 a2[4], b2[2];
#pragma unroll
        for (int mi = 0; mi < 4; ++mi)
            a2[mi] = *(const short8*)&Hs[mi * 16 + lr][kc * 32 + lk * 8];
#pragma unroll
        for (int ni = 0; ni < 2; ++ni)
            b2[ni] = *(const short8*)(w1b + ni * (16 * 256) + kc * 32);
#pragma unroll
        for (int mi = 0; mi < 4; ++mi)
#pragma unroll
            for (int ni = 0; ni < 2; ++ni)
                acc2[mi][ni] = __builtin_amdgcn_mfma_f32_16x16x32_bf16(
                    a2[mi], b2[ni], acc2[mi][ni], 0, 0, 0);
    }
#pragma unroll
    for (int ni = 0; ni < 2; ++ni) {
        int n = w * 32 + ni * 16 + lr;
        float bias = b1[n];
#pragma unroll
        for (int mi = 0; mi < 4; ++mi)
#pragma unroll
            for (int r = 0; r < 4; ++r) {
                int m = mi * 16 + lk * 4 + r;
                int v = v0 + m;
                if (v < V_) {
                    size_t o = ((size_t)b * V_ + v) * C_ + n;
                    out[o] = acc2[mi][ni][r] + bias + x_in[o];
                }
            }
    }
}

// ============================================================================
extern "C" void kernel_launch(void* const* d_in, const int* in_sizes, int n_in,
                              void* d_out, int out_size, void* d_ws, size_t ws_size,
                              hipStream_t stream)
{
    const float* x_in  = (const float*)d_in[0];
    const float* evals = (const float*)d_in[1];
    const float* evecs = (const float*)d_in[2];
    const float* mass  = (const float*)d_in[3];
    const float* gv[3] = {(const float*)d_in[4], (const float*)d_in[7], (const float*)d_in[10]};
    const int*   gr[3] = {(const int*)d_in[5],   (const int*)d_in[8],   (const int*)d_in[11]};
    const int*   gc[3] = {(const int*)d_in[6],   (const int*)d_in[9],   (const int*)d_in[12]};
    const float* dt  = (const float*)d_in[13];
    const float* Aw  = (const float*)d_in[14];
    const float* W0  = (const float*)d_in[15];
    const float* b0  = (const float*)d_in[16];
    const float* W1  = (const float*)d_in[17];
    const float* b1  = (const float*)d_in[18];
    float* out = (float*)d_out;

    // ---- workspace layout (~104 MB; chunk aliases evT/mxT) ----
    float* x_spec = (float*)d_ws;                            // 65536 f32
    us* spec_t = (us*)(x_spec + 65536);                      // 16384
    us* W0b    = spec_t + 16384;                             // 98304
    us* W1b    = W0b + 98304;                                // 32768
    us* Awb    = W1b + 32768;                                // 147456
    us* fb     = Awb + 147456;                               // VP_*384
    us* vf     = fb + (size_t)VP_ * 384;                     // VP_*384
    us* evT    = vf + (size_t)VP_ * 384;                     // 128*VPT_
    us* mxT    = evT + (size_t)128 * VPT_;                   // 128*VPT_
    int* gcnt  = (int*)(mxT + (size_t)128 * VPT_);           // 3*NB_ ints
    // chunk aliases evT+mxT (dead after k_spec_mfma; 22.8 MB <= 25.7 MB)
    uint2* chunk = (uint2*)evT;

    hipMemsetAsync(x_spec, 0, 65536 * sizeof(float), stream);
    k_cvt_all<<<dim3(640), 256, 0, stream>>>(W0, W1, Aw, W0b, W1b, Awb);

    for (int b = 0; b < B_; ++b) {
        hipMemsetAsync(gcnt, 0, 3 * NB_ * sizeof(int), stream);
        k_trans<<<dim3(784), 256, 0, stream>>>(x_in, mass, evecs, mxT, evT, fb, b);
        k_spec_mfma<<<dim3(196), 256, 0, stream>>>(evT, mxT, x_spec, b);
        k_scale2<<<dim3(64), 256, 0, stream>>>(evals, dt, x_spec, spec_t, b);
        k_frombasis_mfma<<<dim3(782), 256, 0, stream>>>(evecs, spec_t, fb, b);
        k_binfill<<<dim3(NBF_, 3), 256, 0, stream>>>(
            gr[0], gr[1], gr[2], gc[0], gc[1], gc[2], gv[0], gv[1], gv[2],
            chunk, gcnt, b);
        k_gather2<<<dim3(NB_, 3), 256, 0, stream>>>(chunk, gcnt, fb, vf);
        k_gf_mfma<<<dim3(782), 256, 0, stream>>>(vf, Awb, fb);
        k_mlp_mfma<<<dim3(782), 256, 0, stream>>>(fb, W0b, b0, W1b, b1, x_in, out, b);
    }
}

// Round 9
// 2205.175 us; speedup vs baseline: 3.5244x; 3.5244x over previous
//
#include <hip/hip_runtime.h>
#include <cstdint>
#include <cstddef>

#define B_   4
#define V_   50000
#define VP_  50048                       // 782*64  (fb/vf row count)
#define VPT_ 50176                       // 784*64 = 196*256 (evT/mxT v-stride)
#define K_   128
#define C_   128
#define NNZ_ 800000
#define HID_ 256

#define CHUNK_  1024
#define NCHUNK_ 49
#define NSLICE_ 8                        // slice = r>>13 in 0..6; x-dim 8 pins slice->XCD

typedef __attribute__((ext_vector_type(8))) short short8;
typedef __attribute__((ext_vector_type(4))) float f32x4;
typedef unsigned short us;

__device__ __forceinline__ us f2b(float f) {
    union { float f; unsigned u; } v; v.f = f;
    unsigned r = v.u + 0x7fffu + ((v.u >> 16) & 1u);
    return (us)(r >> 16);
}
__device__ __forceinline__ float b2f(us h) {
    union { unsigned u; float f; } v; v.u = ((unsigned)h) << 16; return v.f;
}
__device__ __forceinline__ unsigned pk(float lo, float hi) {
    return (unsigned)f2b(lo) | ((unsigned)f2b(hi) << 16);
}
__device__ __forceinline__ short8 cvt8(float4 p0, float4 p1) {
    union { unsigned u[4]; short8 s; } r;
    r.u[0] = pk(p0.x, p0.y); r.u[1] = pk(p0.z, p0.w);
    r.u[2] = pk(p1.x, p1.y); r.u[3] = pk(p1.z, p1.w);
    return r.s;
}

// ============================================================================
// k_cvt_all: W0/W1 bf16 convert + Aw permuted bf16 convert (one dispatch)
// ============================================================================
__global__ __launch_bounds__(256) void k_cvt_all(
    const float* __restrict__ W0, const float* __restrict__ W1,
    const float* __restrict__ Aw,
    us* __restrict__ W0b, us* __restrict__ W1b, us* __restrict__ Awb)
{
    int t = blockIdx.x * 256 + threadIdx.x;          // 163840 threads total
    if (t < 16384) {
        const float* src; us* dst; int i8;
        if (t < 12288) { i8 = t * 8;            src = W0 + i8; dst = W0b + i8; }
        else           { i8 = (t - 12288) * 8;  src = W1 + i8; dst = W1b + i8; }
        float4 x0 = *(const float4*)src;
        float4 x1 = *(const float4*)(src + 4);
        uint4 u;
        u.x = pk(x0.x, x0.y); u.y = pk(x0.z, x0.w);
        u.z = pk(x1.x, x1.y); u.w = pk(x1.z, x1.w);
        *(uint4*)dst = u;
    } else {
        int p  = t - 16384;                          // < 147456
        int p1 = p / 384, p2 = p - p1 * 384;
        int q1 = 3 * (p1 & 127) + (p1 >> 7);
        int q2 = 3 * (p2 & 127) + (p2 >> 7);
        Awb[p] = f2b(Aw[q1 * 384 + q2]);
    }
}

// ============================================================================
// k_trans: fused transpose kernel (known-good)
// ============================================================================
__global__ __launch_bounds__(256) void k_trans(
    const float* __restrict__ x_in, const float* __restrict__ mass,
    const float* __restrict__ evecs,
    us* __restrict__ mxT, us* __restrict__ evT, us* __restrict__ fb, int b)
{
    const int v0  = blockIdx.x * 64;
    const int tid = threadIdx.x;
    __shared__ us ts[128][72];

#pragma unroll
    for (int it = 0; it < 8; ++it) {
        int f   = tid + it * 256;
        int row = f >> 5;
        int col = (f & 31) * 4;
        int v   = v0 + row;
        float4 x = make_float4(0.f, 0.f, 0.f, 0.f);
        float  m = 0.f;
        if (v < V_) {
            x = *(const float4*)&x_in[((size_t)b * V_ + v) * C_ + col];
            m = mass[b * V_ + v];
            uint2 u; u.x = pk(x.x, x.y); u.y = pk(x.z, x.w);
            *(uint2*)&fb[(size_t)v * 384 + col] = u;
        }
        ts[col + 0][row] = f2b(x.x * m); ts[col + 1][row] = f2b(x.y * m);
        ts[col + 2][row] = f2b(x.z * m); ts[col + 3][row] = f2b(x.w * m);
    }
    __syncthreads();
    {
        int c = tid >> 1, half = tid & 1;
#pragma unroll
        for (int q = 0; q < 4; ++q) {
            uint4 u = *(const uint4*)&ts[c][half * 32 + q * 8];
            *(uint4*)&mxT[(size_t)c * VPT_ + v0 + half * 32 + q * 8] = u;
        }
    }
    __syncthreads();

#pragma unroll
    for (int it = 0; it < 8; ++it) {
        int f   = tid + it * 256;
        int row = f >> 5;
        int col = (f & 31) * 4;
        int v   = v0 + row;
        float4 e = (v < V_)
            ? *(const float4*)&evecs[((size_t)b * V_ + v) * K_ + col]
            : make_float4(0.f, 0.f, 0.f, 0.f);
        ts[col + 0][row] = f2b(e.x); ts[col + 1][row] = f2b(e.y);
        ts[col + 2][row] = f2b(e.z); ts[col + 3][row] = f2b(e.w);
    }
    __syncthreads();
    {
        int k = tid >> 1, half = tid & 1;
#pragma unroll
        for (int q = 0; q < 4; ++q) {
            uint4 u = *(const uint4*)&ts[k][half * 32 + q * 8];
            *(uint4*)&evT[(size_t)k * VPT_ + v0 + half * 32 + q * 8] = u;
        }
    }
}

// ============================================================================
// k_spec_mfma: x_spec[b,k,c] += sum_{v-slab} evT[k][v] * mxT[c][v]   (MFMA)
// ============================================================================
__global__ __launch_bounds__(256) void k_spec_mfma(
    const us* __restrict__ evT, const us* __restrict__ mxT,
    float* __restrict__ x_spec, int b)
{
    const int vb  = blockIdx.x * 256;
    const int tid = threadIdx.x;
    const int w   = tid >> 6;
    const int lr  = tid & 15;
    const int lk  = (tid & 63) >> 4;

    f32x4 z = {0.f, 0.f, 0.f, 0.f};
    f32x4 acc[2][8];
#pragma unroll
    for (int mi = 0; mi < 2; ++mi)
#pragma unroll
        for (int ni = 0; ni < 8; ++ni) acc[mi][ni] = z;

#pragma unroll 2
    for (int s = 0; s < 8; ++s) {
        int vo = vb + s * 32 + lk * 8;
        short8 a[2], bf[8];
#pragma unroll
        for (int mi = 0; mi < 2; ++mi)
            a[mi] = *(const short8*)&evT[(size_t)(w * 32 + mi * 16 + lr) * VPT_ + vo];
#pragma unroll
        for (int ni = 0; ni < 8; ++ni)
            bf[ni] = *(const short8*)&mxT[(size_t)(ni * 16 + lr) * VPT_ + vo];
#pragma unroll
        for (int mi = 0; mi < 2; ++mi)
#pragma unroll
            for (int ni = 0; ni < 8; ++ni)
                acc[mi][ni] = __builtin_amdgcn_mfma_f32_16x16x32_bf16(
                    a[mi], bf[ni], acc[mi][ni], 0, 0, 0);
    }
#pragma unroll
    for (int mi = 0; mi < 2; ++mi)
#pragma unroll
        for (int ni = 0; ni < 8; ++ni)
#pragma unroll
            for (int r = 0; r < 4; ++r) {
                int k = w * 32 + mi * 16 + lk * 4 + r;
                int c = ni * 16 + lr;
                atomicAdd(&x_spec[((size_t)b * K_ + k) * C_ + c], acc[mi][ni][r]);
            }
}

// ============================================================================
// k_scale2: spec_t[c][k] = bf16( exp(-evals[b,k]*max(dt[c],1e-8)) * x_spec[b,k,c] )
// ============================================================================
__global__ __launch_bounds__(256) void k_scale2(
    const float* __restrict__ evals, const float* __restrict__ dt,
    const float* __restrict__ x_spec, us* __restrict__ spec_t, int b)
{
    int i = blockIdx.x * 256 + threadIdx.x;    // < 16384
    int c = i >> 7;
    int k = i & 127;
    float t = fmaxf(dt[c], 1e-8f);
    float v = __expf(-evals[b * K_ + k] * t) * x_spec[((size_t)b * K_ + k) * C_ + c];
    spec_t[i] = f2b(v);
}

// ============================================================================
// k_frombasis_mfma: fb[v][128+c] = bf16( sum_k evecs[b,v,k] * spec_t[c][k] )
// ============================================================================
__global__ __launch_bounds__(256) void k_frombasis_mfma(
    const float* __restrict__ evecs, const us* __restrict__ spec_t,
    us* __restrict__ fb, int b)
{
    const int v0  = blockIdx.x * 64;
    const int tid = threadIdx.x;
    const int w   = tid >> 6;
    const int lr  = tid & 15;
    const int lk  = (tid & 63) >> 4;

    f32x4 z = {0.f, 0.f, 0.f, 0.f};
    f32x4 acc[4][2];
#pragma unroll
    for (int mi = 0; mi < 4; ++mi)
#pragma unroll
        for (int ni = 0; ni < 2; ++ni) acc[mi][ni] = z;

#pragma unroll
    for (int ks = 0; ks < 4; ++ks) {
        int ko = ks * 32 + lk * 8;
        short8 a[4], bf[2];
#pragma unroll
        for (int mi = 0; mi < 4; ++mi) {
            int v = v0 + mi * 16 + lr;
            float4 p0 = make_float4(0.f, 0.f, 0.f, 0.f);
            float4 p1 = make_float4(0.f, 0.f, 0.f, 0.f);
            if (v < V_) {
                const float* src = &evecs[((size_t)b * V_ + v) * K_ + ko];
                p0 = *(const float4*)src;
                p1 = *(const float4*)(src + 4);
            }
            a[mi] = cvt8(p0, p1);
        }
#pragma unroll
        for (int ni = 0; ni < 2; ++ni)
            bf[ni] = *(const short8*)&spec_t[(size_t)(w * 32 + ni * 16 + lr) * K_ + ko];
#pragma unroll
        for (int mi = 0; mi < 4; ++mi)
#pragma unroll
            for (int ni = 0; ni < 2; ++ni)
                acc[mi][ni] = __builtin_amdgcn_mfma_f32_16x16x32_bf16(
                    a[mi], bf[ni], acc[mi][ni], 0, 0, 0);
    }
#pragma unroll
    for (int mi = 0; mi < 4; ++mi)
#pragma unroll
        for (int ni = 0; ni < 2; ++ni)
#pragma unroll
            for (int r = 0; r < 4; ++r) {
                int v = v0 + mi * 16 + lk * 4 + r;
                int c = w * 32 + ni * 16 + lr;
                if (v < V_) fb[(size_t)v * 384 + 128 + c] = f2b(acc[mi][ni][r]);
            }
}

// ============================================================================
// CSR build: count -> chunksum -> chunkscan -> ptrwrite -> fill(XCD-pinned)
// ============================================================================
__global__ __launch_bounds__(256) void k_count(
    const int* __restrict__ r0, const int* __restrict__ r1,
    const int* __restrict__ r2, int* __restrict__ cnt, int b)
{
    const int d = blockIdx.y;
    const int e = blockIdx.x * 256 + threadIdx.x;
    const int* rr = (d == 0) ? r0 : (d == 1) ? r1 : r2;
    int r = rr[(size_t)b * NNZ_ + e];
    atomicAdd(&cnt[d * V_ + r], 1);
}

__global__ __launch_bounds__(256) void k_chunksum(
    const int* __restrict__ cnt, int* __restrict__ csum)
{
    const int d  = blockIdx.y;
    const int ch = blockIdx.x;
    const int tid = threadIdx.x;
    int s = 0;
#pragma unroll
    for (int j = 0; j < 4; ++j) {
        int i = ch * CHUNK_ + tid * 4 + j;
        if (i < V_) s += cnt[d * V_ + i];
    }
    __shared__ int sh[256];
    sh[tid] = s;
    __syncthreads();
    for (int off = 128; off > 0; off >>= 1) {
        if (tid < off) sh[tid] += sh[tid + off];
        __syncthreads();
    }
    if (tid == 0) csum[d * NCHUNK_ + ch] = sh[0];
}

__global__ __launch_bounds__(64) void k_chunkscan(
    int* __restrict__ csum, int* __restrict__ ptr)
{
    int d = threadIdx.x;
    if (d < 3) {
        int run = 0;
        for (int ch = 0; ch < NCHUNK_; ++ch) {
            int t = csum[d * NCHUNK_ + ch];
            csum[d * NCHUNK_ + ch] = run;
            run += t;
        }
        ptr[d * (V_ + 1) + V_] = NNZ_;
    }
}

__global__ __launch_bounds__(256) void k_ptrwrite(
    const int* __restrict__ cnt, const int* __restrict__ csum,
    int* __restrict__ ptr)
{
    const int d  = blockIdx.y;
    const int ch = blockIdx.x;
    const int tid = threadIdx.x;
    int v[4];
    int tsum = 0;
#pragma unroll
    for (int j = 0; j < 4; ++j) {
        int i = ch * CHUNK_ + tid * 4 + j;
        int x = (i < V_) ? cnt[d * V_ + i] : 0;
        v[j] = tsum;
        tsum += x;
    }
    __shared__ int sh[256];
    sh[tid] = tsum;
    __syncthreads();
    for (int off = 1; off < 256; off <<= 1) {
        int t = (tid >= off) ? sh[tid - off] : 0;
        __syncthreads();
        sh[tid] += t;
        __syncthreads();
    }
    int excl = sh[tid] - tsum;
    int base = csum[d * NCHUNK_ + ch] + excl;
#pragma unroll
    for (int j = 0; j < 4; ++j) {
        int i = ch * CHUNK_ + tid * 4 + j;
        if (i < V_) ptr[d * (V_ + 1) + i] = base + v[j];
    }
}

// XCD-pinned sliced fill: slice s = r>>13 (0..6) is the FASTEST-VARYING grid
// dim of 8, so all blocks of slice s land on XCD s (x-major round-robin
// dispatch). Destination lines of a slice then live in exactly one XCD's L2 ->
// no cross-XCD line bouncing while the 8 sibling 8B writes of each 64B line
// arrive. Correctness does not depend on the mapping.
__global__ __launch_bounds__(256) void k_fill(
    const int* __restrict__ r0, const int* __restrict__ r1, const int* __restrict__ r2,
    const int* __restrict__ c0, const int* __restrict__ c1, const int* __restrict__ c2,
    const float* __restrict__ v0, const float* __restrict__ v1, const float* __restrict__ v2,
    const int* __restrict__ ptr, int* __restrict__ cnt,
    uint2* __restrict__ svc, int b)
{
    const int s = blockIdx.x;                       // 0..7  -> XCD
    const int d = blockIdx.z;
    const int e = blockIdx.y * 256 + threadIdx.x;
    const int*   rr = (d == 0) ? r0 : (d == 1) ? r1 : r2;
    size_t src = (size_t)b * NNZ_ + e;
    int r = rr[src];
    if ((r >> 13) != s) return;
    const int*   cc = (d == 0) ? c0 : (d == 1) ? c1 : c2;
    const float* vv = (d == 0) ? v0 : (d == 1) ? v1 : v2;
    int k = atomicSub(&cnt[d * V_ + r], 1) - 1;     // leaves cnt zeroed
    int pos = ptr[d * (V_ + 1) + r] + k;
    uint2 ent;
    ent.x = __float_as_uint(vv[src]);
    ent.y = (unsigned)cc[src];
    svc[(size_t)d * NNZ_ + pos] = ent;
}

// ============================================================================
// k_gather: vf[r][d*128+c] = bf16( sum_e val_e * x_diffuse_bf16[col_e][c] )
// one wave per row, 2 bf16/lane; 8-way unrolled for memory-level parallelism.
// ============================================================================
__global__ __launch_bounds__(256) void k_gather(
    const uint2* __restrict__ svc, const int* __restrict__ ptr,
    const us* __restrict__ fb, us* __restrict__ vf)
{
    const int d    = blockIdx.y;
    const int w    = threadIdx.x >> 6;
    const int lane = threadIdx.x & 63;
    const int r    = blockIdx.x * 4 + w;
    int beg = ptr[d * (V_ + 1) + r];
    int end = ptr[d * (V_ + 1) + r + 1];
    const uint2* base = svc + (size_t)d * NNZ_;
    const int lo2 = lane * 2;

    float ax[8], ay[8];
#pragma unroll
    for (int j = 0; j < 8; ++j) { ax[j] = 0.f; ay[j] = 0.f; }

    int i = beg;
    for (; i + 8 <= end; i += 8) {
        uint2 e[8];
#pragma unroll
        for (int j = 0; j < 8; ++j) e[j] = base[i + j];
        unsigned u[8];
#pragma unroll
        for (int j = 0; j < 8; ++j)
            u[j] = *(const unsigned*)&fb[(size_t)e[j].y * 384 + 128 + lo2];
#pragma unroll
        for (int j = 0; j < 8; ++j) {
            float v = __uint_as_float(e[j].x);
            ax[j] += v * b2f((us)(u[j] & 0xffffu));
            ay[j] += v * b2f((us)(u[j] >> 16));
        }
    }
    for (; i < end; ++i) {
        uint2 e0 = base[i];
        unsigned u0 = *(const unsigned*)&fb[(size_t)e0.y * 384 + 128 + lo2];
        float v = __uint_as_float(e0.x);
        ax[0] += v * b2f((us)(u0 & 0xffffu));
        ay[0] += v * b2f((us)(u0 >> 16));
    }
    float sx = ((ax[0] + ax[1]) + (ax[2] + ax[3])) + ((ax[4] + ax[5]) + (ax[6] + ax[7]));
    float sy = ((ay[0] + ay[1]) + (ay[2] + ay[3])) + ((ay[4] + ay[5]) + (ay[6] + ay[7]));
    *(unsigned*)&vf[(size_t)r * 384 + d * 128 + lo2] = pk(sx, sy);
}

// ============================================================================
// k_gf_mfma: Av' = vf @ Awb^T (MFMA bf16), then
// f[v][256+c] = bf16(tanh(sum_d Av'[v][d*128+c] * vf[v][d*128+c]))
// ============================================================================
__global__ __launch_bounds__(256) void k_gf_mfma(
    const us* __restrict__ vf, const us* __restrict__ Awb,
    us* __restrict__ fb)
{
    const int v0  = blockIdx.x * 64;
    const int tid = threadIdx.x;
    const int w   = tid >> 6;
    const int lr  = tid & 15;
    const int lk  = (tid & 63) >> 4;

    f32x4 z = {0.f, 0.f, 0.f, 0.f};
    f32x4 acc[4][3][2];
#pragma unroll
    for (int mi = 0; mi < 4; ++mi)
#pragma unroll
        for (int d = 0; d < 3; ++d)
#pragma unroll
            for (int ci = 0; ci < 2; ++ci) acc[mi][d][ci] = z;

    const us* aa = vf  + (size_t)(v0 + lr) * 384 + lk * 8;
    const us* bb = Awb + (size_t)(w * 32 + lr) * 384 + lk * 8;
#pragma unroll 2
    for (int kc = 0; kc < 12; ++kc) {
        short8 a[4];
#pragma unroll
        for (int mi = 0; mi < 4; ++mi)
            a[mi] = *(const short8*)(aa + mi * (16 * 384) + kc * 32);
        short8 bm[3][2];
#pragma unroll
        for (int d = 0; d < 3; ++d)
#pragma unroll
            for (int ci = 0; ci < 2; ++ci)
                bm[d][ci] = *(const short8*)(bb + (size_t)(d * 128 + ci * 16) * 384 + kc * 32);
#pragma unroll
        for (int mi = 0; mi < 4; ++mi)
#pragma unroll
            for (int d = 0; d < 3; ++d)
#pragma unroll
                for (int ci = 0; ci < 2; ++ci)
                    acc[mi][d][ci] = __builtin_amdgcn_mfma_f32_16x16x32_bf16(
                        a[mi], bm[d][ci], acc[mi][d][ci], 0, 0, 0);
    }
#pragma unroll
    for (int mi = 0; mi < 4; ++mi)
#pragma unroll
        for (int r = 0; r < 4; ++r) {
            int m = mi * 16 + lk * 4 + r;
            int v = v0 + m;
            if (v < V_) {
#pragma unroll
                for (int ci = 0; ci < 2; ++ci) {
                    int c = w * 32 + ci * 16 + lr;
                    float s = 0.f;
#pragma unroll
                    for (int d = 0; d < 3; ++d)
                        s += acc[mi][d][ci][r] * b2f(vf[(size_t)v * 384 + d * 128 + c]);
                    fb[(size_t)v * 384 + 256 + c] = f2b(tanhf(s));
                }
            }
        }
}

// ============================================================================
// k_mlp_mfma: h = relu(f @ W0^T + b0) (bf16, LDS); out = h @ W1^T + b1 + x_in
// ============================================================================
__global__ __launch_bounds__(256) void k_mlp_mfma(
    const us* __restrict__ fb,
    const us* __restrict__ W0b, const float* __restrict__ b0,
    const us* __restrict__ W1b, const float* __restrict__ b1,
    const float* __restrict__ x_in, float* __restrict__ out, int b)
{
    const int v0  = blockIdx.x * 64;
    const int tid = threadIdx.x;
    const int w   = tid >> 6;
    const int lr  = tid & 15;
    const int lk  = (tid & 63) >> 4;

    __shared__ us Hs[64][264];

    f32x4 z = {0.f, 0.f, 0.f, 0.f};
    f32x4 acc[4][4];
#pragma unroll
    for (int mi = 0; mi < 4; ++mi)
#pragma unroll
        for (int ni = 0; ni < 4; ++ni) acc[mi][ni] = z;

    const us* fa = fb  + (size_t)(v0 + lr) * 384 + lk * 8;
    const us* wb = W0b + (size_t)(w * 64 + lr) * 384 + lk * 8;
#pragma unroll 4
    for (int kc = 0; kc < 12; ++kc) {
        short8 a[4], bbf[4];
#pragma unroll
        for (int mi = 0; mi < 4; ++mi)
            a[mi] = *(const short8*)(fa + mi * (16 * 384) + kc * 32);
#pragma unroll
        for (int ni = 0; ni < 4; ++ni)
            bbf[ni] = *(const short8*)(wb + ni * (16 * 384) + kc * 32);
#pragma unroll
        for (int mi = 0; mi < 4; ++mi)
#pragma unroll
            for (int ni = 0; ni < 4; ++ni)
                acc[mi][ni] = __builtin_amdgcn_mfma_f32_16x16x32_bf16(
                    a[mi], bbf[ni], acc[mi][ni], 0, 0, 0);
    }
#pragma unroll
    for (int ni = 0; ni < 4; ++ni) {
        int n = w * 64 + ni * 16 + lr;
        float bias = b0[n];
#pragma unroll
        for (int mi = 0; mi < 4; ++mi)
#pragma unroll
            for (int r = 0; r < 4; ++r) {
                int m = mi * 16 + lk * 4 + r;
                Hs[m][n] = f2b(fmaxf(acc[mi][ni][r] + bias, 0.f));
            }
    }
    __syncthreads();

    f32x4 acc2[4][2];
#pragma unroll
    for (int mi = 0; mi < 4; ++mi)
#pragma unroll
        for (int ni = 0; ni < 2; ++ni) acc2[mi][ni] = z;

    const us* w1b = W1b + (size_t)(w * 32 + lr) * 256 + lk * 8;
#pragma unroll 4
    for (int kc = 0; kc < 8; ++kc) {
        short8 a2[4], b2[2];
#pragma unroll
        for (int mi = 0; mi < 4; ++mi)
            a2[mi] = *(const short8*)&Hs[mi * 16 + lr][kc * 32 + lk * 8];
#pragma unroll
        for (int ni = 0; ni < 2; ++ni)
            b2[ni] = *(const short8*)(w1b + ni * (16 * 256) + kc * 32);
#pragma unroll
        for (int mi = 0; mi < 4; ++mi)
#pragma unroll
            for (int ni = 0; ni < 2; ++ni)
                acc2[mi][ni] = __builtin_amdgcn_mfma_f32_16x16x32_bf16(
                    a2[mi], b2[ni], acc2[mi][ni], 0, 0, 0);
    }
#pragma unroll
    for (int ni = 0; ni < 2; ++ni) {
        int n = w * 32 + ni * 16 + lr;
        float bias = b1[n];
#pragma unroll
        for (int mi = 0; mi < 4; ++mi)
#pragma unroll
            for (int r = 0; r < 4; ++r) {
                int m = mi * 16 + lk * 4 + r;
                int v = v0 + m;
                if (v < V_) {
                    size_t o = ((size_t)b * V_ + v) * C_ + n;
                    out[o] = acc2[mi][ni][r] + bias + x_in[o];
                }
            }
    }
}

// ============================================================================
extern "C" void kernel_launch(void* const* d_in, const int* in_sizes, int n_in,
                              void* d_out, int out_size, void* d_ws, size_t ws_size,
                              hipStream_t stream)
{
    const float* x_in  = (const float*)d_in[0];
    const float* evals = (const float*)d_in[1];
    const float* evecs = (const float*)d_in[2];
    const float* mass  = (const float*)d_in[3];
    const float* gv[3] = {(const float*)d_in[4], (const float*)d_in[7], (const float*)d_in[10]};
    const int*   gr[3] = {(const int*)d_in[5],   (const int*)d_in[8],   (const int*)d_in[11]};
    const int*   gc[3] = {(const int*)d_in[6],   (const int*)d_in[9],   (const int*)d_in[12]};
    const float* dt  = (const float*)d_in[13];
    const float* Aw  = (const float*)d_in[14];
    const float* W0  = (const float*)d_in[15];
    const float* b0  = (const float*)d_in[16];
    const float* W1  = (const float*)d_in[17];
    const float* b1  = (const float*)d_in[18];
    float* out = (float*)d_out;

    // ---- workspace layout (≈124 MB) ----
    float* x_spec = (float*)d_ws;                            // 65536 f32
    us* spec_t = (us*)(x_spec + 65536);                      // 16384
    us* W0b    = spec_t + 16384;                             // 98304
    us* W1b    = W0b + 98304;                                // 32768
    us* Awb    = W1b + 32768;                                // 147456
    us* fb     = Awb + 147456;                               // VP_*384
    us* vf     = fb + (size_t)VP_ * 384;                     // VP_*384
    us* evT    = vf + (size_t)VP_ * 384;                     // 128*VPT_
    us* mxT    = evT + (size_t)128 * VPT_;                   // 128*VPT_
    uint2* svc = (uint2*)(mxT + (size_t)128 * VPT_);         // 3*NNZ_ uint2
    int* ptr   = (int*)(svc + 3 * (size_t)NNZ_);             // 3*(V_+1)
    int* cnt   = ptr + 3 * (V_ + 1);                         // 3*V_
    int* csum  = cnt + 3 * V_;                               // 3*NCHUNK_

    hipMemsetAsync(x_spec, 0, 65536 * sizeof(float), stream);
    hipMemsetAsync(cnt, 0, 3 * V_ * sizeof(int), stream);    // k_fill re-zeroes it each batch
    k_cvt_all<<<dim3(640), 256, 0, stream>>>(W0, W1, Aw, W0b, W1b, Awb);

    for (int b = 0; b < B_; ++b) {
        k_trans<<<dim3(784), 256, 0, stream>>>(x_in, mass, evecs, mxT, evT, fb, b);
        k_spec_mfma<<<dim3(196), 256, 0, stream>>>(evT, mxT, x_spec, b);
        k_scale2<<<dim3(64), 256, 0, stream>>>(evals, dt, x_spec, spec_t, b);
        k_frombasis_mfma<<<dim3(782), 256, 0, stream>>>(evecs, spec_t, fb, b);
        k_count<<<dim3(3125, 3), 256, 0, stream>>>(gr[0], gr[1], gr[2], cnt, b);
        k_chunksum<<<dim3(NCHUNK_, 3), 256, 0, stream>>>(cnt, csum);
        k_chunkscan<<<dim3(1), 64, 0, stream>>>(csum, ptr);
        k_ptrwrite<<<dim3(NCHUNK_, 3), 256, 0, stream>>>(cnt, csum, ptr);
        k_fill<<<dim3(NSLICE_, 3125, 3), 256, 0, stream>>>(
            gr[0], gr[1], gr[2], gc[0], gc[1], gc[2], gv[0], gv[1], gv[2],
            ptr, cnt, svc, b);
        k_gather<<<dim3(12500, 3), 256, 0, stream>>>(svc, ptr, fb, vf);
        k_gf_mfma<<<dim3(782), 256, 0, stream>>>(vf, Awb, fb);
        k_mlp_mfma<<<dim3(782), 256, 0, stream>>>(fb, W0b, b0, W1b, b1, x_in, out, b);
    }
}

// Round 10
// 1506.653 us; speedup vs baseline: 5.1584x; 1.4636x over previous
//
#include <hip/hip_runtime.h>
#include <cstdint>
#include <cstddef>

#define B_   4
#define V_   50000
#define VP_  50048                       // 782*64  (fb/vf row count)
#define VPT_ 50176                       // 784*64 = 196*256 (evT/mxT v-stride)
#define K_   128
#define C_   128
#define NNZ_ 800000
#define HID_ 256

#define NB_   391                        // buckets of 128 rows
#define CAP_  2560                       // per-(d,bucket) capacity (mean 2048, +11 sigma)
#define CH_   4096                       // entries per binfill block
#define NBF_  196                        // ceil(NNZ_/CH_)

typedef __attribute__((ext_vector_type(8))) short short8;
typedef __attribute__((ext_vector_type(4))) float f32x4;
typedef unsigned short us;

__device__ __forceinline__ us f2b(float f) {
    union { float f; unsigned u; } v; v.f = f;
    unsigned r = v.u + 0x7fffu + ((v.u >> 16) & 1u);
    return (us)(r >> 16);
}
__device__ __forceinline__ float b2f(us h) {
    union { unsigned u; float f; } v; v.u = ((unsigned)h) << 16; return v.f;
}
__device__ __forceinline__ unsigned pk(float lo, float hi) {
    return (unsigned)f2b(lo) | ((unsigned)f2b(hi) << 16);
}
__device__ __forceinline__ short8 cvt8(float4 p0, float4 p1) {
    union { unsigned u[4]; short8 s; } r;
    r.u[0] = pk(p0.x, p0.y); r.u[1] = pk(p0.z, p0.w);
    r.u[2] = pk(p1.x, p1.y); r.u[3] = pk(p1.z, p1.w);
    return r.s;
}

// ============================================================================
// k_cvt_all: W0/W1 bf16 convert + Aw permuted bf16 convert (one dispatch)
// ============================================================================
__global__ __launch_bounds__(256) void k_cvt_all(
    const float* __restrict__ W0, const float* __restrict__ W1,
    const float* __restrict__ Aw,
    us* __restrict__ W0b, us* __restrict__ W1b, us* __restrict__ Awb)
{
    int t = blockIdx.x * 256 + threadIdx.x;          // 163840 threads total
    if (t < 16384) {
        const float* src; us* dst; int i8;
        if (t < 12288) { i8 = t * 8;            src = W0 + i8; dst = W0b + i8; }
        else           { i8 = (t - 12288) * 8;  src = W1 + i8; dst = W1b + i8; }
        float4 x0 = *(const float4*)src;
        float4 x1 = *(const float4*)(src + 4);
        uint4 u;
        u.x = pk(x0.x, x0.y); u.y = pk(x0.z, x0.w);
        u.z = pk(x1.x, x1.y); u.w = pk(x1.z, x1.w);
        *(uint4*)dst = u;
    } else {
        int p  = t - 16384;                          // < 147456
        int p1 = p / 384, p2 = p - p1 * 384;
        int q1 = 3 * (p1 & 127) + (p1 >> 7);
        int q2 = 3 * (p2 & 127) + (p2 >> 7);
        Awb[p] = f2b(Aw[q1 * 384 + q2]);
    }
}

// ============================================================================
// k_trans: fused transpose kernel (known-good)
// ============================================================================
__global__ __launch_bounds__(256) void k_trans(
    const float* __restrict__ x_in, const float* __restrict__ mass,
    const float* __restrict__ evecs,
    us* __restrict__ mxT, us* __restrict__ evT, us* __restrict__ fb, int b)
{
    const int v0  = blockIdx.x * 64;
    const int tid = threadIdx.x;
    __shared__ us ts[128][72];

#pragma unroll
    for (int it = 0; it < 8; ++it) {
        int f   = tid + it * 256;
        int row = f >> 5;
        int col = (f & 31) * 4;
        int v   = v0 + row;
        float4 x = make_float4(0.f, 0.f, 0.f, 0.f);
        float  m = 0.f;
        if (v < V_) {
            x = *(const float4*)&x_in[((size_t)b * V_ + v) * C_ + col];
            m = mass[b * V_ + v];
            uint2 u; u.x = pk(x.x, x.y); u.y = pk(x.z, x.w);
            *(uint2*)&fb[(size_t)v * 384 + col] = u;
        }
        ts[col + 0][row] = f2b(x.x * m); ts[col + 1][row] = f2b(x.y * m);
        ts[col + 2][row] = f2b(x.z * m); ts[col + 3][row] = f2b(x.w * m);
    }
    __syncthreads();
    {
        int c = tid >> 1, half = tid & 1;
#pragma unroll
        for (int q = 0; q < 4; ++q) {
            uint4 u = *(const uint4*)&ts[c][half * 32 + q * 8];
            *(uint4*)&mxT[(size_t)c * VPT_ + v0 + half * 32 + q * 8] = u;
        }
    }
    __syncthreads();

#pragma unroll
    for (int it = 0; it < 8; ++it) {
        int f   = tid + it * 256;
        int row = f >> 5;
        int col = (f & 31) * 4;
        int v   = v0 + row;
        float4 e = (v < V_)
            ? *(const float4*)&evecs[((size_t)b * V_ + v) * K_ + col]
            : make_float4(0.f, 0.f, 0.f, 0.f);
        ts[col + 0][row] = f2b(e.x); ts[col + 1][row] = f2b(e.y);
        ts[col + 2][row] = f2b(e.z); ts[col + 3][row] = f2b(e.w);
    }
    __syncthreads();
    {
        int k = tid >> 1, half = tid & 1;
#pragma unroll
        for (int q = 0; q < 4; ++q) {
            uint4 u = *(const uint4*)&ts[k][half * 32 + q * 8];
            *(uint4*)&evT[(size_t)k * VPT_ + v0 + half * 32 + q * 8] = u;
        }
    }
}

// ============================================================================
// k_spec_mfma: x_spec[b,k,c] += sum_{v-slab} evT[k][v] * mxT[c][v]   (MFMA)
// ============================================================================
__global__ __launch_bounds__(256) void k_spec_mfma(
    const us* __restrict__ evT, const us* __restrict__ mxT,
    float* __restrict__ x_spec, int b)
{
    const int vb  = blockIdx.x * 256;
    const int tid = threadIdx.x;
    const int w   = tid >> 6;
    const int lr  = tid & 15;
    const int lk  = (tid & 63) >> 4;

    f32x4 z = {0.f, 0.f, 0.f, 0.f};
    f32x4 acc[2][8];
#pragma unroll
    for (int mi = 0; mi < 2; ++mi)
#pragma unroll
        for (int ni = 0; ni < 8; ++ni) acc[mi][ni] = z;

#pragma unroll 2
    for (int s = 0; s < 8; ++s) {
        int vo = vb + s * 32 + lk * 8;
        short8 a[2], bf[8];
#pragma unroll
        for (int mi = 0; mi < 2; ++mi)
            a[mi] = *(const short8*)&evT[(size_t)(w * 32 + mi * 16 + lr) * VPT_ + vo];
#pragma unroll
        for (int ni = 0; ni < 8; ++ni)
            bf[ni] = *(const short8*)&mxT[(size_t)(ni * 16 + lr) * VPT_ + vo];
#pragma unroll
        for (int mi = 0; mi < 2; ++mi)
#pragma unroll
            for (int ni = 0; ni < 8; ++ni)
                acc[mi][ni] = __builtin_amdgcn_mfma_f32_16x16x32_bf16(
                    a[mi], bf[ni], acc[mi][ni], 0, 0, 0);
    }
#pragma unroll
    for (int mi = 0; mi < 2; ++mi)
#pragma unroll
        for (int ni = 0; ni < 8; ++ni)
#pragma unroll
            for (int r = 0; r < 4; ++r) {
                int k = w * 32 + mi * 16 + lk * 4 + r;
                int c = ni * 16 + lr;
                atomicAdd(&x_spec[((size_t)b * K_ + k) * C_ + c], acc[mi][ni][r]);
            }
}

// ============================================================================
// k_scale2: spec_t[c][k] = bf16( exp(-evals[b,k]*max(dt[c],1e-8)) * x_spec[b,k,c] )
// ============================================================================
__global__ __launch_bounds__(256) void k_scale2(
    const float* __restrict__ evals, const float* __restrict__ dt,
    const float* __restrict__ x_spec, us* __restrict__ spec_t, int b)
{
    int i = blockIdx.x * 256 + threadIdx.x;    // < 16384
    int c = i >> 7;
    int k = i & 127;
    float t = fmaxf(dt[c], 1e-8f);
    float v = __expf(-evals[b * K_ + k] * t) * x_spec[((size_t)b * K_ + k) * C_ + c];
    spec_t[i] = f2b(v);
}

// ============================================================================
// k_frombasis_mfma: fb[v][128+c] = bf16( sum_k evecs[b,v,k] * spec_t[c][k] )
// ============================================================================
__global__ __launch_bounds__(256) void k_frombasis_mfma(
    const float* __restrict__ evecs, const us* __restrict__ spec_t,
    us* __restrict__ fb, int b)
{
    const int v0  = blockIdx.x * 64;
    const int tid = threadIdx.x;
    const int w   = tid >> 6;
    const int lr  = tid & 15;
    const int lk  = (tid & 63) >> 4;

    f32x4 z = {0.f, 0.f, 0.f, 0.f};
    f32x4 acc[4][2];
#pragma unroll
    for (int mi = 0; mi < 4; ++mi)
#pragma unroll
        for (int ni = 0; ni < 2; ++ni) acc[mi][ni] = z;

#pragma unroll
    for (int ks = 0; ks < 4; ++ks) {
        int ko = ks * 32 + lk * 8;
        short8 a[4], bf[2];
#pragma unroll
        for (int mi = 0; mi < 4; ++mi) {
            int v = v0 + mi * 16 + lr;
            float4 p0 = make_float4(0.f, 0.f, 0.f, 0.f);
            float4 p1 = make_float4(0.f, 0.f, 0.f, 0.f);
            if (v < V_) {
                const float* src = &evecs[((size_t)b * V_ + v) * K_ + ko];
                p0 = *(const float4*)src;
                p1 = *(const float4*)(src + 4);
            }
            a[mi] = cvt8(p0, p1);
        }
#pragma unroll
        for (int ni = 0; ni < 2; ++ni)
            bf[ni] = *(const short8*)&spec_t[(size_t)(w * 32 + ni * 16 + lr) * K_ + ko];
#pragma unroll
        for (int mi = 0; mi < 4; ++mi)
#pragma unroll
            for (int ni = 0; ni < 2; ++ni)
                acc[mi][ni] = __builtin_amdgcn_mfma_f32_16x16x32_bf16(
                    a[mi], bf[ni], acc[mi][ni], 0, 0, 0);
    }
#pragma unroll
    for (int mi = 0; mi < 4; ++mi)
#pragma unroll
        for (int ni = 0; ni < 2; ++ni)
#pragma unroll
            for (int r = 0; r < 4; ++r) {
                int v = v0 + mi * 16 + lk * 4 + r;
                int c = w * 32 + ni * 16 + lr;
                if (v < V_) fb[(size_t)v * 384 + 128 + c] = f2b(acc[mi][ni][r]);
            }
}

// ============================================================================
// k_binfill: LDS-binned bucket scatter (round-7 proven). Block = CH_ edges of
// one direction. Histogram buckets (q=r>>7) in LDS, scan, reorder into LDS,
// flush each bucket as a contiguous run into chunk[(d*NB_+q)*CAP_ + cursor].
// Entry: {val fp32, (q<<23)|(rlow<<16)|col}.
// ============================================================================
__global__ __launch_bounds__(256) void k_binfill(
    const int* __restrict__ r0, const int* __restrict__ r1, const int* __restrict__ r2,
    const int* __restrict__ c0, const int* __restrict__ c1, const int* __restrict__ c2,
    const float* __restrict__ v0, const float* __restrict__ v1, const float* __restrict__ v2,
    uint2* __restrict__ chunk, int* __restrict__ gcnt, int b)
{
    const int d   = blockIdx.y;
    const int e0  = blockIdx.x * CH_;
    const int tid = threadIdx.x;
    const int*   rr = (d == 0) ? r0 : (d == 1) ? r1 : r2;
    const int*   cc = (d == 0) ? c0 : (d == 1) ? c1 : c2;
    const float* vv = (d == 0) ? v0 : (d == 1) ? v1 : v2;

    __shared__ int   hist[NB_];
    __shared__ int   cur[NB_];
    __shared__ int   base[NB_];
    __shared__ int   gbase[NB_];
    __shared__ uint2 buf[CH_];           // 32 KB

    for (int i = tid; i < NB_; i += 256) { hist[i] = 0; cur[i] = 0; }
    __syncthreads();

    int rloc[16];
#pragma unroll
    for (int j = 0; j < 16; ++j) {
        int e = e0 + j * 256 + tid;
        int r = (e < NNZ_) ? rr[(size_t)b * NNZ_ + e] : -1;
        rloc[j] = r;
        if (r >= 0) atomicAdd(&hist[r >> 7], 1);
    }
    __syncthreads();

    // exclusive scan of hist -> base (wave 0: 7 buckets/lane + shfl scan)
    if (tid < 64) {
        int q0 = tid * 7;
        int loc[7];
        int s = 0;
#pragma unroll
        for (int j = 0; j < 7; ++j) {
            int q = q0 + j;
            int h = (q < NB_) ? hist[q] : 0;
            loc[j] = s; s += h;
        }
        int inc = s;
        for (int off = 1; off < 64; off <<= 1) {
            int t = __shfl_up(inc, off, 64);
            if (tid >= off) inc += t;
        }
        int excl = inc - s;
#pragma unroll
        for (int j = 0; j < 7; ++j) {
            int q = q0 + j;
            if (q < NB_) base[q] = excl + loc[j];
        }
    }
    __syncthreads();

    // reorder into LDS staging buffer
#pragma unroll
    for (int j = 0; j < 16; ++j) {
        int r = rloc[j];
        if (r < 0) continue;
        int e = e0 + j * 256 + tid;
        int q = r >> 7;
        int off = atomicAdd(&cur[q], 1);
        int pos = base[q] + off;
        uint2 ent;
        ent.x = __float_as_uint(vv[(size_t)b * NNZ_ + e]);
        ent.y = ((unsigned)q << 23) | ((unsigned)(r & 127) << 16)
              | (unsigned)cc[(size_t)b * NNZ_ + e];
        buf[pos] = ent;
    }
    __syncthreads();

    // reserve global space per bucket
    for (int q = tid; q < NB_; q += 256) {
        int c = cur[q];
        if (c > 0) gbase[q] = atomicAdd(&gcnt[d * NB_ + q], c);
    }
    __syncthreads();

    // flush: consecutive i -> same bucket run -> coalesced
    const int tot = min(CH_, NNZ_ - e0);
#pragma unroll
    for (int j = 0; j < 16; ++j) {
        int i = tid + j * 256;
        if (i >= tot) break;
        uint2 ent = buf[i];
        int q   = ent.y >> 23;
        int dst = gbase[q] + (i - base[q]);
        if (dst < CAP_)
            chunk[(size_t)(d * NB_ + q) * CAP_ + dst] =
                make_uint2(ent.x, ent.y & 0x7fffffu);   // keep rlow|col
    }
}

// ============================================================================
// k_sortbkt: in-place per-bucket CSR sort + local ptr emit.
// Block = (bucket q, direction d). Loads <=CAP_ entries to registers,
// 128-bin histogram + scan, permute into LDS in row order, write back
// coalesced in place; ptr[(d*NB_+q)*129 + rl] = bucket_base + excl[rl].
// ============================================================================
__global__ __launch_bounds__(256) void k_sortbkt(
    uint2* __restrict__ chunk, const int* __restrict__ gcnt,
    int* __restrict__ ptr)
{
    const int q   = blockIdx.x;
    const int d   = blockIdx.y;
    const int tid = threadIdx.x;
    const int cnt = min(gcnt[d * NB_ + q], CAP_);
    uint2* cb = chunk + (size_t)(d * NB_ + q) * CAP_;
    const int pbase = (d * NB_ + q) * CAP_;     // absolute chunk index base

    __shared__ int   hist[129];
    __shared__ int   lcur[128];
    __shared__ uint2 obuf[CAP_];                // 20 KB

    for (int i = tid; i < 128; i += 256) { hist[i] = 0; lcur[i] = 0; }
    __syncthreads();

    uint2 ent[10];                              // CAP_/256 = 10
    int n = 0;
    for (int i = tid; i < cnt; i += 256) {
        ent[n] = cb[i];
        atomicAdd(&hist[(ent[n].y >> 16) & 127], 1);
        ++n;
    }
    __syncthreads();

    if (tid < 64) {                             // exclusive scan over 128 bins
        int a0 = hist[tid * 2], a1 = hist[tid * 2 + 1];
        int s = a0 + a1;
        int inc = s;
        for (int off = 1; off < 64; off <<= 1) {
            int t = __shfl_up(inc, off, 64);
            if (tid >= off) inc += t;
        }
        int excl = inc - s;
        hist[tid * 2]     = excl;
        hist[tid * 2 + 1] = excl + a0;
        if (tid == 63) hist[128] = inc;         // total
    }
    __syncthreads();

    for (int j = 0; j < n; ++j) {               // permute into CSR order
        int rl  = (ent[j].y >> 16) & 127;
        int dst = hist[rl] + atomicAdd(&lcur[rl], 1);
        obuf[dst] = make_uint2(ent[j].x, ent[j].y & 0xffffu);   // col only
    }
    __syncthreads();

    for (int i = tid; i < cnt; i += 256) cb[i] = obuf[i];       // coalesced
    for (int i = tid; i <= 128; i += 256)
        ptr[(d * NB_ + q) * 129 + i] = pbase + hist[i];
}

// ============================================================================
// k_gather: vf[r][d*128+c] = bf16( sum_e val_e * x_diffuse_bf16[col_e][c] )
// one wave per row, 2 bf16/lane; 8-way unrolled. Entries from sorted chunk.
// ============================================================================
__global__ __launch_bounds__(256) void k_gather(
    const uint2* __restrict__ chunk, const int* __restrict__ ptr,
    const us* __restrict__ fb, us* __restrict__ vf)
{
    const int d    = blockIdx.y;
    const int w    = threadIdx.x >> 6;
    const int lane = threadIdx.x & 63;
    const int r    = blockIdx.x * 4 + w;
    const int idx  = (d * NB_ + (r >> 7)) * 129 + (r & 127);
    int beg = ptr[idx];
    int end = ptr[idx + 1];
    const int lo2 = lane * 2;

    float ax[8], ay[8];
#pragma unroll
    for (int j = 0; j < 8; ++j) { ax[j] = 0.f; ay[j] = 0.f; }

    int i = beg;
    for (; i + 8 <= end; i += 8) {
        uint2 e[8];
#pragma unroll
        for (int j = 0; j < 8; ++j) e[j] = chunk[i + j];
        unsigned u[8];
#pragma unroll
        for (int j = 0; j < 8; ++j)
            u[j] = *(const unsigned*)&fb[(size_t)e[j].y * 384 + 128 + lo2];
#pragma unroll
        for (int j = 0; j < 8; ++j) {
            float v = __uint_as_float(e[j].x);
            ax[j] += v * b2f((us)(u[j] & 0xffffu));
            ay[j] += v * b2f((us)(u[j] >> 16));
        }
    }
    for (; i < end; ++i) {
        uint2 e0 = chunk[i];
        unsigned u0 = *(const unsigned*)&fb[(size_t)e0.y * 384 + 128 + lo2];
        float v = __uint_as_float(e0.x);
        ax[0] += v * b2f((us)(u0 & 0xffffu));
        ay[0] += v * b2f((us)(u0 >> 16));
    }
    float sx = ((ax[0] + ax[1]) + (ax[2] + ax[3])) + ((ax[4] + ax[5]) + (ax[6] + ax[7]));
    float sy = ((ay[0] + ay[1]) + (ay[2] + ay[3])) + ((ay[4] + ay[5]) + (ay[6] + ay[7]));
    *(unsigned*)&vf[(size_t)r * 384 + d * 128 + lo2] = pk(sx, sy);
}

// ============================================================================
// k_gf_mfma: Av' = vf @ Awb^T (MFMA bf16), then
// f[v][256+c] = bf16(tanh(sum_d Av'[v][d*128+c] * vf[v][d*128+c]))
// ============================================================================
__global__ __launch_bounds__(256) void k_gf_mfma(
    const us* __restrict__ vf, const us* __restrict__ Awb,
    us* __restrict__ fb)
{
    const int v0  = blockIdx.x * 64;
    const int tid = threadIdx.x;
    const int w   = tid >> 6;
    const int lr  = tid & 15;
    const int lk  = (tid & 63) >> 4;

    f32x4 z = {0.f, 0.f, 0.f, 0.f};
    f32x4 acc[4][3][2];
#pragma unroll
    for (int mi = 0; mi < 4; ++mi)
#pragma unroll
        for (int d = 0; d < 3; ++d)
#pragma unroll
            for (int ci = 0; ci < 2; ++ci) acc[mi][d][ci] = z;

    const us* aa = vf  + (size_t)(v0 + lr) * 384 + lk * 8;
    const us* bb = Awb + (size_t)(w * 32 + lr) * 384 + lk * 8;
#pragma unroll 2
    for (int kc = 0; kc < 12; ++kc) {
        short8 a[4];
#pragma unroll
        for (int mi = 0; mi < 4; ++mi)
            a[mi] = *(const short8*)(aa + mi * (16 * 384) + kc * 32);
        short8 bm[3][2];
#pragma unroll
        for (int d = 0; d < 3; ++d)
#pragma unroll
            for (int ci = 0; ci < 2; ++ci)
                bm[d][ci] = *(const short8*)(bb + (size_t)(d * 128 + ci * 16) * 384 + kc * 32);
#pragma unroll
        for (int mi = 0; mi < 4; ++mi)
#pragma unroll
            for (int d = 0; d < 3; ++d)
#pragma unroll
                for (int ci = 0; ci < 2; ++ci)
                    acc[mi][d][ci] = __builtin_amdgcn_mfma_f32_16x16x32_bf16(
                        a[mi], bm[d][ci], acc[mi][d][ci], 0, 0, 0);
    }
#pragma unroll
    for (int mi = 0; mi < 4; ++mi)
#pragma unroll
        for (int r = 0; r < 4; ++r) {
            int m = mi * 16 + lk * 4 + r;
            int v = v0 + m;
            if (v < V_) {
#pragma unroll
                for (int ci = 0; ci < 2; ++ci) {
                    int c = w * 32 + ci * 16 + lr;
                    float s = 0.f;
#pragma unroll
                    for (int d = 0; d < 3; ++d)
                        s += acc[mi][d][ci][r] * b2f(vf[(size_t)v * 384 + d * 128 + c]);
                    fb[(size_t)v * 384 + 256 + c] = f2b(tanhf(s));
                }
            }
        }
}

// ============================================================================
// k_mlp_mfma: h = relu(f @ W0^T + b0) (bf16, LDS); out = h @ W1^T + b1 + x_in
// ============================================================================
__global__ __launch_bounds__(256) void k_mlp_mfma(
    const us* __restrict__ fb,
    const us* __restrict__ W0b, const float* __restrict__ b0,
    const us* __restrict__ W1b, const float* __restrict__ b1,
    const float* __restrict__ x_in, float* __restrict__ out, int b)
{
    const int v0  = blockIdx.x * 64;
    const int tid = threadIdx.x;
    const int w   = tid >> 6;
    const int lr  = tid & 15;
    const int lk  = (tid & 63) >> 4;

    __shared__ us Hs[64][264];

    f32x4 z = {0.f, 0.f, 0.f, 0.f};
    f32x4 acc[4][4];
#pragma unroll
    for (int mi = 0; mi < 4; ++mi)
#pragma unroll
        for (int ni = 0; ni < 4; ++ni) acc[mi][ni] = z;

    const us* fa = fb  + (size_t)(v0 + lr) * 384 + lk * 8;
    const us* wb = W0b + (size_t)(w * 64 + lr) * 384 + lk * 8;
#pragma unroll 4
    for (int kc = 0; kc < 12; ++kc) {
        short8 a[4], bbf[4];
#pragma unroll
        for (int mi = 0; mi < 4; ++mi)
            a[mi] = *(const short8*)(fa + mi * (16 * 384) + kc * 32);
#pragma unroll
        for (int ni = 0; ni < 4; ++ni)
            bbf[ni] = *(const short8*)(wb + ni * (16 * 384) + kc * 32);
#pragma unroll
        for (int mi = 0; mi < 4; ++mi)
#pragma unroll
            for (int ni = 0; ni < 4; ++ni)
                acc[mi][ni] = __builtin_amdgcn_mfma_f32_16x16x32_bf16(
                    a[mi], bbf[ni], acc[mi][ni], 0, 0, 0);
    }
#pragma unroll
    for (int ni = 0; ni < 4; ++ni) {
        int n = w * 64 + ni * 16 + lr;
        float bias = b0[n];
#pragma unroll
        for (int mi = 0; mi < 4; ++mi)
#pragma unroll
            for (int r = 0; r < 4; ++r) {
                int m = mi * 16 + lk * 4 + r;
                Hs[m][n] = f2b(fmaxf(acc[mi][ni][r] + bias, 0.f));
            }
    }
    __syncthreads();

    f32x4 acc2[4][2];
#pragma unroll
    for (int mi = 0; mi < 4; ++mi)
#pragma unroll
        for (int ni = 0; ni < 2; ++ni) acc2[mi][ni] = z;

    const us* w1b = W1b + (size_t)(w * 32 + lr) * 256 + lk * 8;
#pragma unroll 4
    for (int kc = 0; kc < 8; ++kc) {
        short8 a2[4], b2[2];
#pragma unroll
        for (int mi = 0; mi < 4; ++mi)
            a2[mi] = *(const short8*)&Hs[mi * 16 + lr][kc * 32 + lk * 8];
#pragma unroll
        for (int ni = 0; ni < 2; ++ni)
            b2[ni] = *(const short8*)(w1b + ni * (16 * 256) + kc * 32);
#pragma unroll
        for (int mi = 0; mi < 4; ++mi)
#pragma unroll
            for (int ni = 0; ni < 2; ++ni)
                acc2[mi][ni] = __builtin_amdgcn_mfma_f32_16x16x32_bf16(
                    a2[mi], b2[ni], acc2[mi][ni], 0, 0, 0);
    }
#pragma unroll
    for (int ni = 0; ni < 2; ++ni) {
        int n = w * 32 + ni * 16 + lr;
        float bias = b1[n];
#pragma unroll
        for (int mi = 0; mi < 4; ++mi)
#pragma unroll
            for (int r = 0; r < 4; ++r) {
                int m = mi * 16 + lk * 4 + r;
                int v = v0 + m;
                if (v < V_) {
                    size_t o = ((size_t)b * V_ + v) * C_ + n;
                    out[o] = acc2[mi][ni][r] + bias + x_in[o];
                }
            }
    }
}

// ============================================================================
extern "C" void kernel_launch(void* const* d_in, const int* in_sizes, int n_in,
                              void* d_out, int out_size, void* d_ws, size_t ws_size,
                              hipStream_t stream)
{
    const float* x_in  = (const float*)d_in[0];
    const float* evals = (const float*)d_in[1];
    const float* evecs = (const float*)d_in[2];
    const float* mass  = (const float*)d_in[3];
    const float* gv[3] = {(const float*)d_in[4], (const float*)d_in[7], (const float*)d_in[10]};
    const int*   gr[3] = {(const int*)d_in[5],   (const int*)d_in[8],   (const int*)d_in[11]};
    const int*   gc[3] = {(const int*)d_in[6],   (const int*)d_in[9],   (const int*)d_in[12]};
    const float* dt  = (const float*)d_in[13];
    const float* Aw  = (const float*)d_in[14];
    const float* W0  = (const float*)d_in[15];
    const float* b0  = (const float*)d_in[16];
    const float* W1  = (const float*)d_in[17];
    const float* b1  = (const float*)d_in[18];
    float* out = (float*)d_out;

    // ---- workspace layout (≈105 MB; chunk aliases evT/mxT) ----
    float* x_spec = (float*)d_ws;                            // 65536 f32
    us* spec_t = (us*)(x_spec + 65536);                      // 16384
    us* W0b    = spec_t + 16384;                             // 98304
    us* W1b    = W0b + 98304;                                // 32768
    us* Awb    = W1b + 32768;                                // 147456
    us* fb     = Awb + 147456;                               // VP_*384
    us* vf     = fb + (size_t)VP_ * 384;                     // VP_*384
    us* evT    = vf + (size_t)VP_ * 384;                     // 128*VPT_
    us* mxT    = evT + (size_t)128 * VPT_;                   // 128*VPT_
    int* gcnt  = (int*)(mxT + (size_t)128 * VPT_);           // 3*NB_
    int* ptr   = gcnt + 3 * NB_;                             // 3*NB_*129
    // chunk aliases evT+mxT (dead after k_spec_mfma; 24.0 MB <= 25.7 MB)
    uint2* chunk = (uint2*)evT;

    hipMemsetAsync(x_spec, 0, 65536 * sizeof(float), stream);
    k_cvt_all<<<dim3(640), 256, 0, stream>>>(W0, W1, Aw, W0b, W1b, Awb);

    for (int b = 0; b < B_; ++b) {
        hipMemsetAsync(gcnt, 0, 3 * NB_ * sizeof(int), stream);
        k_trans<<<dim3(784), 256, 0, stream>>>(x_in, mass, evecs, mxT, evT, fb, b);
        k_spec_mfma<<<dim3(196), 256, 0, stream>>>(evT, mxT, x_spec, b);
        k_scale2<<<dim3(64), 256, 0, stream>>>(evals, dt, x_spec, spec_t, b);
        k_frombasis_mfma<<<dim3(782), 256, 0, stream>>>(evecs, spec_t, fb, b);
        k_binfill<<<dim3(NBF_, 3), 256, 0, stream>>>(
            gr[0], gr[1], gr[2], gc[0], gc[1], gc[2], gv[0], gv[1], gv[2],
            chunk, gcnt, b);
        k_sortbkt<<<dim3(NB_, 3), 256, 0, stream>>>(chunk, gcnt, ptr);
        k_gather<<<dim3(12500, 3), 256, 0, stream>>>(chunk, ptr, fb, vf);
        k_gf_mfma<<<dim3(782), 256, 0, stream>>>(vf, Awb, fb);
        k_mlp_mfma<<<dim3(782), 256, 0, stream>>>(fb, W0b, b0, W1b, b1, x_in, out, b);
    }
}